// Round 4
// baseline (444.735 us; speedup 1.0000x reference)
//
#include <hip/hip_runtime.h>

#define DIN 2048
#define DOUT 2048
#define NHEADS 16
#define HDIM 128
#define LATENT 256
#define BB 2
#define SS 2048
#define MTOT (BB*SS)
#define QLD (DOUT + LATENT)   // fused q|latent row stride = 2304
#define KLD (2*DOUT)          // fused k|v row stride = 4096

using bf16 = __bf16;
using bf16x8 = __attribute__((ext_vector_type(8))) __bf16;
using f32x4 = __attribute__((ext_vector_type(4))) float;

__device__ __forceinline__ void gload16(const bf16* g, bf16* l) {
    __builtin_amdgcn_global_load_lds(
        (const __attribute__((address_space(1))) void*)g,
        (__attribute__((address_space(3))) void*)l, 16, 0, 0);
}

// ---------------- cast fp32 -> bf16 (vectorized) ----------------
__global__ void cast_f32_bf16(const float* __restrict__ in, bf16* __restrict__ out, int n) {
    int i = (blockIdx.x * blockDim.x + threadIdx.x) * 8;
    if (i >= n) return;
    float4 a = *(const float4*)(in + i);
    float4 b = *(const float4*)(in + i + 4);
    bf16x8 o;
    o[0] = (bf16)a.x; o[1] = (bf16)a.y; o[2] = (bf16)a.z; o[3] = (bf16)a.w;
    o[4] = (bf16)b.x; o[5] = (bf16)b.y; o[6] = (bf16)b.z; o[7] = (bf16)b.w;
    *(bf16x8*)(out + i) = o;
}

// ---------------- transpose + cast: W[R][C] fp32 -> WT[C][R] bf16 ----------------
__global__ void transpose_cast(const float* __restrict__ W, bf16* __restrict__ WT, int R, int C) {
    __shared__ float tile[32][33];
    int c0 = blockIdx.x * 32, r0 = blockIdx.y * 32;
    int tx = threadIdx.x & 31, ty = threadIdx.x >> 5;
    #pragma unroll
    for (int i = ty; i < 32; i += 8)
        tile[i][tx] = W[(size_t)(r0 + i) * C + c0 + tx];
    __syncthreads();
    #pragma unroll
    for (int i = ty; i < 32; i += 8)
        WT[(size_t)(c0 + i) * R + r0 + tx] = (bf16)tile[tx][i];
}

// ---------------- transpose v (cols 2048.. of kvb) -> vT[b][h][d][s] ----------------
__global__ void transpose_v(const bf16* __restrict__ v, bf16* __restrict__ vT) {
    int bh = blockIdx.z;
    int s0 = blockIdx.x * 32, d0 = blockIdx.y * 32;
    __shared__ bf16 t[32][33];
    int tx = threadIdx.x & 31, ty = threadIdx.x >> 5;
    int b = bh >> 4, h = bh & 15;
    #pragma unroll
    for (int i = ty; i < 32; i += 8)
        t[i][tx] = v[(size_t)(b * SS + s0 + i) * KLD + h * HDIM + d0 + tx];
    __syncthreads();
    #pragma unroll
    for (int i = ty; i < 32; i += 8)
        vT[((size_t)bh * HDIM + d0 + i) * SS + s0 + tx] = t[tx][i];
}

// ---------------- GEMM: C[M][*] = A[M][K] @ BT[N][K]^T (+bias) ----------------
// m97 structure; strided A (Ald) and C (Cld) for fused outputs; XCD-swizzled grid.
template<bool OUT_F32, bool BIAS>
__global__ __launch_bounds__(256) void gemm_bt(const bf16* __restrict__ A,
        const bf16* __restrict__ BT, void* __restrict__ Cp,
        const float* __restrict__ bias, const int Kdim, const int Ald,
        const int Ndim, const int Cld) {
    // XCD-aware bijective swizzle (all grids here are %8==0)
    const int nwg = gridDim.x * gridDim.y;
    int orig = blockIdx.y * gridDim.x + blockIdx.x;
    int swz = (orig & 7) * (nwg >> 3) + (orig >> 3);
    const int n0 = (swz % gridDim.x) * 128, m0 = (swz / gridDim.x) * 128;

    const int tid = threadIdx.x, wave = tid >> 6, lane = tid & 63;
    const int wm = wave >> 1, wn = wave & 1;
    const int lr = lane & 15, lg = lane >> 4;
    __shared__ __align__(16) bf16 As[128][32];
    __shared__ __align__(16) bf16 Bs[128][32];
    f32x4 acc[4][4];
    #pragma unroll
    for (int i = 0; i < 4; ++i)
        #pragma unroll
        for (int j = 0; j < 4; ++j) acc[i][j] = (f32x4){0.f, 0.f, 0.f, 0.f};

    const int sr = lane >> 2;
    const int sc = (lane & 3) * 8;
    const bf16* ga = A  + (size_t)(m0 + wave * 16 + sr) * Ald + sc;
    const bf16* gb = BT + (size_t)(n0 + wave * 16 + sr) * Kdim + sc;
    const size_t strideA64 = (size_t)64 * Ald;
    const size_t strideB64 = (size_t)64 * Kdim;
    bf16* lAd = &As[wave * 16][0];
    bf16* lBd = &Bs[wave * 16][0];

    for (int k0 = 0; k0 < Kdim; k0 += 32) {
        gload16(ga,             lAd);
        gload16(ga + strideA64, lAd + 64 * 32);
        gload16(gb,             lBd);
        gload16(gb + strideB64, lBd + 64 * 32);
        ga += 32; gb += 32;
        __syncthreads();
        bf16x8 af[4], bfr[4];
        #pragma unroll
        for (int i = 0; i < 4; ++i)
            af[i] = *(const bf16x8*)&As[wm * 64 + i * 16 + lr][lg * 8];
        #pragma unroll
        for (int j = 0; j < 4; ++j)
            bfr[j] = *(const bf16x8*)&Bs[wn * 64 + j * 16 + lr][lg * 8];
        #pragma unroll
        for (int i = 0; i < 4; ++i)
            #pragma unroll
            for (int j = 0; j < 4; ++j)
                acc[i][j] = __builtin_amdgcn_mfma_f32_16x16x32_bf16(af[i], bfr[j], acc[i][j], 0, 0, 0);
        __syncthreads();
    }
    #pragma unroll
    for (int i = 0; i < 4; ++i)
        #pragma unroll
        for (int j = 0; j < 4; ++j) {
            const int r0 = m0 + wm * 64 + i * 16 + lg * 4;
            const int c = n0 + wn * 64 + j * 16 + lr;
            #pragma unroll
            for (int r2 = 0; r2 < 4; ++r2) {
                float v = acc[i][j][r2];
                if (BIAS) v += bias[c];
                if (OUT_F32) ((float*)Cp)[(size_t)(r0 + r2) * Cld + c] = v;
                else         ((bf16*)Cp)[(size_t)(r0 + r2) * Cld + c] = (bf16)v;
            }
        }
}

// ---------------- causal flash attention ----------------
// grid (16, 32); block does q-tiles bx and 31-bx. XOR-swizzled LDS, async staging.
__global__ __launch_bounds__(256) void attn_kernel(const bf16* __restrict__ q,
        const bf16* __restrict__ k, const bf16* __restrict__ vT, bf16* __restrict__ ctx) {
    // XCD swizzle: 64 consecutive swz-ids (4 bh) per XCD -> K/V L2 locality
    int orig = blockIdx.y * 16 + blockIdx.x;
    int swz = (orig & 7) * 64 + (orig >> 3);
    const int bx = swz & 15, bh = swz >> 4;
    const int b = bh >> 4, h = bh & 15;
    const int tid = threadIdx.x, wave = tid >> 6, lane = tid & 63;
    const int lr = lane & 15, lg = lane >> 4;

    __shared__ __align__(16) bf16 KsL[64 * 128];   // [kc][d] ^ ((kc&7)<<4) on bytes
    __shared__ __align__(16) bf16 VsL[128 * 64];   // [d][kc] ^ ((d&7)<<4)
    __shared__ __align__(16) bf16 PsL[64 * 64];    // [qr][kc] ^ ((qr&7)<<4)

    char* KsB = (char*)KsL; char* VsB = (char*)VsL; char* PsB = (char*)PsL;

    // staging geometry (per thread): K: row=tid>>2, 4x16B chunks at (tid&3)*64 + u*16
    //                                V: row=tid>>1, 4x16B chunks at (tid&1)*64 + u*16
    const int krow = tid >> 2, kc0b = (tid & 3) * 64;
    const int vrow = tid >> 1, vc0b = (tid & 1) * 64;
    int kOff[4], vOff[4];
    #pragma unroll
    for (int u = 0; u < 4; ++u) {
        kOff[u] = (krow * 256 + kc0b + u * 16) ^ ((krow & 7) << 4);
        vOff[u] = (vrow * 128 + vc0b + u * 16) ^ ((vrow & 7) << 4);
    }
    const bf16* gkb = k  + ((size_t)b * SS + krow) * KLD + h * HDIM + (tid & 3) * 32;
    const bf16* gvb = vT + ((size_t)bh * HDIM + vrow) * SS + (tid & 1) * 32;

    const float C = 0.12751744f;  // log2(e)/sqrt(128)

    for (int half = 0; half < 2; ++half) {
        const int qt = half ? (31 - bx) : bx;
        const int q0 = qt * 64;

        bf16x8 qf[4];
        const bf16* qbase = q + ((size_t)(b * SS + q0 + wave * 16 + lr)) * QLD + h * HDIM;
        #pragma unroll
        for (int d = 0; d < 4; ++d) qf[d] = *(const bf16x8*)(qbase + d * 32 + lg * 8);

        f32x4 o[8];
        #pragma unroll
        for (int i = 0; i < 8; ++i) o[i] = (f32x4){0.f, 0.f, 0.f, 0.f};
        float m_i[4], l_i[4];
        #pragma unroll
        for (int r = 0; r < 4; ++r) { m_i[r] = -3.0e38f; l_i[r] = 0.f; }

        const int nkt = qt + 1;
        bf16x8 kreg[4], vreg[4];
        // preload tile 0
        #pragma unroll
        for (int u = 0; u < 4; ++u) {
            kreg[u] = *(const bf16x8*)(gkb + (size_t)0 * 64 * KLD + u * 8);
            vreg[u] = *(const bf16x8*)(gvb + 0 * 64 + u * 8);
        }
        #pragma unroll
        for (int u = 0; u < 4; ++u) {
            *(bf16x8*)(KsB + kOff[u]) = kreg[u];
            *(bf16x8*)(VsB + vOff[u]) = vreg[u];
        }
        __syncthreads();

        for (int kt = 0; kt < nkt; ++kt) {
            const int kbase = kt * 64;
            const bool have_next = (kt + 1 < nkt);
            if (have_next) {  // issue next tile's loads early; consumed after barrier
                const bf16* gk = gkb + (size_t)(kt + 1) * 64 * KLD;
                const bf16* gv = gvb + (kt + 1) * 64;
                #pragma unroll
                for (int u = 0; u < 4; ++u) {
                    kreg[u] = *(const bf16x8*)(gk + u * 8);
                    vreg[u] = *(const bf16x8*)(gv + u * 8);
                }
            }

            // S = Q @ K^T (raw scores)
            f32x4 sacc[4];
            #pragma unroll
            for (int nf = 0; nf < 4; ++nf) sacc[nf] = (f32x4){0.f, 0.f, 0.f, 0.f};
            __builtin_amdgcn_s_setprio(1);
            #pragma unroll
            for (int nf = 0; nf < 4; ++nf)
                #pragma unroll
                for (int d = 0; d < 4; ++d) {
                    int row = nf * 16 + lr;
                    bf16x8 kf = *(const bf16x8*)(KsB + ((row * 256 + d * 64 + lg * 16) ^ ((row & 7) << 4)));
                    sacc[nf] = __builtin_amdgcn_mfma_f32_16x16x32_bf16(qf[d], kf, sacc[nf], 0, 0, 0);
                }
            __builtin_amdgcn_s_setprio(0);

            float sv[4][4];
            const bool maskt = (kbase + 63 > q0);
            #pragma unroll
            for (int nf = 0; nf < 4; ++nf)
                #pragma unroll
                for (int r = 0; r < 4; ++r) {
                    float s = sacc[nf][r];
                    if (maskt) {
                        int qr = q0 + wave * 16 + lg * 4 + r;
                        int kc = kbase + nf * 16 + lr;
                        if (qr < kc) s = -3.0e38f;
                    }
                    sv[nf][r] = s;
                }
            float corr[4];
            #pragma unroll
            for (int r = 0; r < 4; ++r) {
                float v = fmaxf(fmaxf(sv[0][r], sv[1][r]), fmaxf(sv[2][r], sv[3][r]));
                #pragma unroll
                for (int off = 1; off < 16; off <<= 1) v = fmaxf(v, __shfl_xor(v, off));
                float mnew = fmaxf(m_i[r], v);
                corr[r] = __builtin_amdgcn_exp2f((m_i[r] - mnew) * C);
                m_i[r] = mnew;
            }
            float rsum[4] = {0.f, 0.f, 0.f, 0.f};
            #pragma unroll
            for (int nf = 0; nf < 4; ++nf)
                #pragma unroll
                for (int r = 0; r < 4; ++r) {
                    float p = __builtin_amdgcn_exp2f((sv[nf][r] - m_i[r]) * C);
                    rsum[r] += p;
                    int prow = wave * 16 + lg * 4 + r;
                    *(bf16*)(PsB + ((prow * 128 + (nf * 16 + lr) * 2) ^ ((prow & 7) << 4))) = (bf16)p;
                }
            #pragma unroll
            for (int r = 0; r < 4; ++r) {
                float v = rsum[r];
                #pragma unroll
                for (int off = 1; off < 16; off <<= 1) v += __shfl_xor(v, off);
                l_i[r] = l_i[r] * corr[r] + v;
            }
            #pragma unroll
            for (int df = 0; df < 8; ++df)
                #pragma unroll
                for (int r = 0; r < 4; ++r) o[df][r] *= corr[r];

            // O += P @ V
            __builtin_amdgcn_s_setprio(1);
            #pragma unroll
            for (int ks = 0; ks < 2; ++ks) {
                int prow = wave * 16 + lr;
                bf16x8 pf = *(const bf16x8*)(PsB + ((prow * 128 + ks * 64 + lg * 16) ^ ((prow & 7) << 4)));
                #pragma unroll
                for (int df = 0; df < 8; ++df) {
                    int vr2 = df * 16 + lr;
                    bf16x8 vf = *(const bf16x8*)(VsB + ((vr2 * 128 + ks * 64 + lg * 16) ^ ((vr2 & 7) << 4)));
                    o[df] = __builtin_amdgcn_mfma_f32_16x16x32_bf16(pf, vf, o[df], 0, 0, 0);
                }
            }
            __builtin_amdgcn_s_setprio(0);
            __syncthreads();   // all waves done reading K/V LDS
            if (have_next) {
                #pragma unroll
                for (int u = 0; u < 4; ++u) {
                    *(bf16x8*)(KsB + kOff[u]) = kreg[u];
                    *(bf16x8*)(VsB + vOff[u]) = vreg[u];
                }
            }
            __syncthreads();
        }

        #pragma unroll
        for (int r = 0; r < 4; ++r) {
            float inv = 1.0f / l_i[r];
            #pragma unroll
            for (int df = 0; df < 8; ++df) {
                int rrow = q0 + wave * 16 + lg * 4 + r;
                int col = h * HDIM + df * 16 + lr;
                ctx[(size_t)(b * SS + rrow) * DOUT + col] = (bf16)(o[df][r] * inv);
            }
        }
    }
}

extern "C" void kernel_launch(void* const* d_in, const int* in_sizes, int n_in,
                              void* d_out, int out_size, void* d_ws, size_t ws_size,
                              hipStream_t stream) {
    const float* x    = (const float*)d_in[0];
    const float* Wq   = (const float*)d_in[1];
    const float* Wdkv = (const float*)d_in[2];
    const float* Wuk  = (const float*)d_in[3];
    const float* Wuv  = (const float*)d_in[4];
    const float* Wout = (const float*)d_in[5];
    const float* bout = (const float*)d_in[6];

    char* ws = (char*)d_ws;
    size_t off = 0;
    auto alloc = [&](size_t bytes) { char* p = ws + off; off = (off + bytes + 255) & ~255ULL; return p; };
    bf16* xb    = (bf16*)alloc((size_t)MTOT * DIN * 2);
    bf16* WqT   = (bf16*)alloc((size_t)DOUT * DIN * 2);     // adjacent:
    bf16* WdkvT = (bf16*)alloc((size_t)LATENT * DIN * 2);   //   WqT||WdkvT = [2304][2048]
    bf16* WukT  = (bf16*)alloc((size_t)DOUT * LATENT * 2);  // adjacent:
    bf16* WuvT  = (bf16*)alloc((size_t)DOUT * LATENT * 2);  //   WukT||WuvT = [4096][256]
    bf16* WoutT = (bf16*)alloc((size_t)DOUT * DOUT * 2);
    bf16* qlat  = (bf16*)alloc((size_t)MTOT * QLD * 2);     // [4096][2304]: q | latent
    bf16* kvb   = (bf16*)alloc((size_t)MTOT * KLD * 2);     // [4096][4096]: k | v
    bf16* vT    = (bf16*)alloc((size_t)BB * NHEADS * HDIM * SS * 2);
    bf16* ctx   = (bf16*)alloc((size_t)MTOT * DOUT * 2);

    cast_f32_bf16<<<(MTOT * DIN) / 8 / 256, 256, 0, stream>>>(x, xb, MTOT * DIN);
    transpose_cast<<<dim3(DOUT / 32, DIN / 32), 256, 0, stream>>>(Wq, WqT, DIN, DOUT);
    transpose_cast<<<dim3(LATENT / 32, DIN / 32), 256, 0, stream>>>(Wdkv, WdkvT, DIN, LATENT);
    transpose_cast<<<dim3(DOUT / 32, LATENT / 32), 256, 0, stream>>>(Wuk, WukT, LATENT, DOUT);
    transpose_cast<<<dim3(DOUT / 32, LATENT / 32), 256, 0, stream>>>(Wuv, WuvT, LATENT, DOUT);
    transpose_cast<<<dim3(DOUT / 32, DOUT / 32), 256, 0, stream>>>(Wout, WoutT, DOUT, DOUT);

    // fused [q | latent] = xb @ [WqT||WdkvT]^T
    gemm_bt<false, false><<<dim3(QLD / 128, MTOT / 128), 256, 0, stream>>>(
        xb, WqT, qlat, nullptr, DIN, DIN, QLD, QLD);
    // fused [k | v] = latent @ [WukT||WuvT]^T
    gemm_bt<false, false><<<dim3(KLD / 128, MTOT / 128), 256, 0, stream>>>(
        qlat + DOUT, WukT, kvb, nullptr, LATENT, QLD, KLD, KLD);

    transpose_v<<<dim3(SS / 32, HDIM / 32, BB * NHEADS), 256, 0, stream>>>(kvb + DOUT, vT);

    attn_kernel<<<dim3(16, BB * NHEADS), 256, 0, stream>>>(qlat, kvb, vT, ctx);

    gemm_bt<true, true><<<dim3(DOUT / 128, MTOT / 128), 256, 0, stream>>>(
        ctx, WoutT, d_out, bout, DOUT, DOUT, DOUT, DOUT);
}

// Round 5
// 379.916 us; speedup vs baseline: 1.1706x; 1.1706x over previous
//
#include <hip/hip_runtime.h>

#define DIN 2048
#define DOUT 2048
#define NHEADS 16
#define HDIM 128
#define LATENT 256
#define BB 2
#define SS 2048
#define MTOT (BB*SS)
#define QLD (DOUT + LATENT)   // fused q|latent row stride = 2304
#define KLD (2*DOUT)          // fused k|v row stride = 4096

using bf16 = __bf16;
using bf16x8 = __attribute__((ext_vector_type(8))) __bf16;
using f32x4 = __attribute__((ext_vector_type(4))) float;

__device__ __forceinline__ void gload16(const bf16* g, bf16* l) {
    __builtin_amdgcn_global_load_lds(
        (const __attribute__((address_space(1))) void*)g,
        (__attribute__((address_space(3))) void*)l, 16, 0, 0);
}

// ---------------- cast fp32 -> bf16 (vectorized) ----------------
__global__ void cast_f32_bf16(const float* __restrict__ in, bf16* __restrict__ out, int n) {
    int i = (blockIdx.x * blockDim.x + threadIdx.x) * 8;
    if (i >= n) return;
    float4 a = *(const float4*)(in + i);
    float4 b = *(const float4*)(in + i + 4);
    bf16x8 o;
    o[0] = (bf16)a.x; o[1] = (bf16)a.y; o[2] = (bf16)a.z; o[3] = (bf16)a.w;
    o[4] = (bf16)b.x; o[5] = (bf16)b.y; o[6] = (bf16)b.z; o[7] = (bf16)b.w;
    *(bf16x8*)(out + i) = o;
}

// ---------------- transpose + cast: W[R][C] fp32 -> WT[C][R] bf16 ----------------
__global__ void transpose_cast(const float* __restrict__ W, bf16* __restrict__ WT, int R, int C) {
    __shared__ float tile[32][33];
    int c0 = blockIdx.x * 32, r0 = blockIdx.y * 32;
    int tx = threadIdx.x & 31, ty = threadIdx.x >> 5;
    #pragma unroll
    for (int i = ty; i < 32; i += 8)
        tile[i][tx] = W[(size_t)(r0 + i) * C + c0 + tx];
    __syncthreads();
    #pragma unroll
    for (int i = ty; i < 32; i += 8)
        WT[(size_t)(c0 + i) * R + r0 + tx] = (bf16)tile[tx][i];
}

// ---------------- transpose v (cols 2048.. of kvb) -> vT[b][h][d][s] ----------------
__global__ void transpose_v(const bf16* __restrict__ v, bf16* __restrict__ vT) {
    int bh = blockIdx.z;
    int s0 = blockIdx.x * 32, d0 = blockIdx.y * 32;
    __shared__ bf16 t[32][33];
    int tx = threadIdx.x & 31, ty = threadIdx.x >> 5;
    int b = bh >> 4, h = bh & 15;
    #pragma unroll
    for (int i = ty; i < 32; i += 8)
        t[i][tx] = v[(size_t)(b * SS + s0 + i) * KLD + h * HDIM + d0 + tx];
    __syncthreads();
    #pragma unroll
    for (int i = ty; i < 32; i += 8)
        vT[((size_t)bh * HDIM + d0 + i) * SS + s0 + tx] = t[tx][i];
}

// ---------------- GEMM: C[M][*] = A[M][K] @ BT[N][K]^T (+bias) ----------------
// m97 structure; strided A (Ald) and C (Cld) for fused outputs; XCD-swizzled grid.
template<bool OUT_F32, bool BIAS>
__global__ __launch_bounds__(256) void gemm_bt(const bf16* __restrict__ A,
        const bf16* __restrict__ BT, void* __restrict__ Cp,
        const float* __restrict__ bias, const int Kdim, const int Ald,
        const int Ndim, const int Cld) {
    const int nwg = gridDim.x * gridDim.y;
    int orig = blockIdx.y * gridDim.x + blockIdx.x;
    int swz = (orig & 7) * (nwg >> 3) + (orig >> 3);
    const int n0 = (swz % gridDim.x) * 128, m0 = (swz / gridDim.x) * 128;

    const int tid = threadIdx.x, wave = tid >> 6, lane = tid & 63;
    const int wm = wave >> 1, wn = wave & 1;
    const int lr = lane & 15, lg = lane >> 4;
    __shared__ __align__(16) bf16 As[128][32];
    __shared__ __align__(16) bf16 Bs[128][32];
    f32x4 acc[4][4];
    #pragma unroll
    for (int i = 0; i < 4; ++i)
        #pragma unroll
        for (int j = 0; j < 4; ++j) acc[i][j] = (f32x4){0.f, 0.f, 0.f, 0.f};

    const int sr = lane >> 2;
    const int sc = (lane & 3) * 8;
    const bf16* ga = A  + (size_t)(m0 + wave * 16 + sr) * Ald + sc;
    const bf16* gb = BT + (size_t)(n0 + wave * 16 + sr) * Kdim + sc;
    const size_t strideA64 = (size_t)64 * Ald;
    const size_t strideB64 = (size_t)64 * Kdim;
    bf16* lAd = &As[wave * 16][0];
    bf16* lBd = &Bs[wave * 16][0];

    for (int k0 = 0; k0 < Kdim; k0 += 32) {
        gload16(ga,             lAd);
        gload16(ga + strideA64, lAd + 64 * 32);
        gload16(gb,             lBd);
        gload16(gb + strideB64, lBd + 64 * 32);
        ga += 32; gb += 32;
        __syncthreads();
        bf16x8 af[4], bfr[4];
        #pragma unroll
        for (int i = 0; i < 4; ++i)
            af[i] = *(const bf16x8*)&As[wm * 64 + i * 16 + lr][lg * 8];
        #pragma unroll
        for (int j = 0; j < 4; ++j)
            bfr[j] = *(const bf16x8*)&Bs[wn * 64 + j * 16 + lr][lg * 8];
        #pragma unroll
        for (int i = 0; i < 4; ++i)
            #pragma unroll
            for (int j = 0; j < 4; ++j)
                acc[i][j] = __builtin_amdgcn_mfma_f32_16x16x32_bf16(af[i], bfr[j], acc[i][j], 0, 0, 0);
        __syncthreads();
    }
    #pragma unroll
    for (int i = 0; i < 4; ++i)
        #pragma unroll
        for (int j = 0; j < 4; ++j) {
            const int r0 = m0 + wm * 64 + i * 16 + lg * 4;
            const int c = n0 + wn * 64 + j * 16 + lr;
            #pragma unroll
            for (int r2 = 0; r2 < 4; ++r2) {
                float v = acc[i][j][r2];
                if (BIAS) v += bias[c];
                if (OUT_F32) ((float*)Cp)[(size_t)(r0 + r2) * Cld + c] = v;
                else         ((bf16*)Cp)[(size_t)(r0 + r2) * Cld + c] = (bf16)v;
            }
        }
}

// ---------------- causal flash attention ----------------
// grid (16, 32); block does q-tiles bx and 31-bx (33 K-tiles total, uniform).
// K/V double-buffered in LDS via global_load_lds from PRE-SWIZZLED global
// addresses (linear LDS dest, XOR-swizzled read side — same involution).
// ONE barrier per K-tile.
__global__ __launch_bounds__(256, 4) void attn_kernel(const bf16* __restrict__ q,
        const bf16* __restrict__ k, const bf16* __restrict__ vT, bf16* __restrict__ ctx) {
    // XCD swizzle: 64 consecutive swz-ids (4 bh) per XCD -> K/V L2 locality
    int orig = blockIdx.y * 16 + blockIdx.x;
    int swz = (orig & 7) * 64 + (orig >> 3);
    const int bx = swz & 15, bh = swz >> 4;
    const int b = bh >> 4, h = bh & 15;
    const int tid = threadIdx.x, wave = tid >> 6, lane = tid & 63;
    const int lr = lane & 15, lg = lane >> 4;

    __shared__ __align__(16) char KsB[2 * 16384];   // [buf][kc][d], byte ^ ((kc&7)<<4)
    __shared__ __align__(16) char VsB[2 * 16384];   // [buf][d][kc], byte ^ ((d&7)<<4)
    __shared__ __align__(16) char PsB[64 * 128];    // [qr][kc],    byte ^ ((qr&7)<<4)

    // staging: LDS byte X = wave*4096 + c*1024 + lane*16 (linear dest).
    // K tile rows 256B: row = X>>8, col = (lane&15)*16; source col pre-XORed.
    int krow[4], kcolE[4];
    #pragma unroll
    for (int c = 0; c < 4; ++c) {
        krow[c] = wave * 16 + c * 4 + (lane >> 4);
        kcolE[c] = ((((lane & 15) * 16) ^ ((krow[c] & 7) << 4)) >> 1);
    }
    // V tile rows 128B: row = wave*32 + c*8 + (lane>>3), col = (lane&7)*16
    const int vrow0 = wave * 32 + (lane >> 3);
    const int vcolE = ((((lane & 7) * 16) ^ ((lane >> 3) << 4)) >> 1);

    const bf16* kbaseP = k  + (size_t)b * SS * KLD + h * HDIM;
    const bf16* vbaseP = vT + (size_t)bh * HDIM * SS;

    const float C = 0.12752602f;  // log2(e)/sqrt(128)

    int cur = 0;
    for (int half = 0; half < 2; ++half) {
        const int qt = half ? (31 - bx) : bx;
        const int q0 = qt * 64;

        bf16x8 qf[4];
        const bf16* qbase = q + ((size_t)(b * SS + q0 + wave * 16 + lr)) * QLD + h * HDIM;
        #pragma unroll
        for (int d = 0; d < 4; ++d) qf[d] = *(const bf16x8*)(qbase + d * 32 + lg * 8);

        f32x4 o[8];
        #pragma unroll
        for (int i = 0; i < 8; ++i) o[i] = (f32x4){0.f, 0.f, 0.f, 0.f};
        float m_i[4], l_i[4];
        #pragma unroll
        for (int r = 0; r < 4; ++r) { m_i[r] = -3.0e38f; l_i[r] = 0.f; }

        const int nkt = qt + 1;

        // stage tile 0 into buf[cur]
        {
            bf16* dK = (bf16*)(KsB + cur * 16384 + wave * 4096);
            bf16* dV = (bf16*)(VsB + cur * 16384 + wave * 4096);
            #pragma unroll
            for (int c = 0; c < 4; ++c) {
                gload16(kbaseP + (size_t)krow[c] * KLD + kcolE[c], dK + c * 512);
                gload16(vbaseP + (size_t)(vrow0 + c * 8) * SS + vcolE, dV + c * 512);
            }
        }
        __syncthreads();

        for (int kt = 0; kt < nkt; ++kt) {
            const int kbase = kt * 64;
            if (kt + 1 < nkt) {   // async prefetch next tile into other buffer
                const int kb2 = kbase + 64;
                bf16* dK = (bf16*)(KsB + (cur ^ 1) * 16384 + wave * 4096);
                bf16* dV = (bf16*)(VsB + (cur ^ 1) * 16384 + wave * 4096);
                #pragma unroll
                for (int c = 0; c < 4; ++c) {
                    gload16(kbaseP + (size_t)(kb2 + krow[c]) * KLD + kcolE[c], dK + c * 512);
                    gload16(vbaseP + (size_t)(vrow0 + c * 8) * SS + kb2 + vcolE, dV + c * 512);
                }
            }
            const char* KB = KsB + cur * 16384;
            const char* VB = VsB + cur * 16384;

            // S = Q @ K^T (raw scores)
            f32x4 sacc[4];
            #pragma unroll
            for (int nf = 0; nf < 4; ++nf) sacc[nf] = (f32x4){0.f, 0.f, 0.f, 0.f};
            __builtin_amdgcn_s_setprio(1);
            #pragma unroll
            for (int nf = 0; nf < 4; ++nf)
                #pragma unroll
                for (int d = 0; d < 4; ++d) {
                    int row = nf * 16 + lr;
                    bf16x8 kf = *(const bf16x8*)(KB + ((row * 256 + d * 64 + lg * 16) ^ ((row & 7) << 4)));
                    sacc[nf] = __builtin_amdgcn_mfma_f32_16x16x32_bf16(qf[d], kf, sacc[nf], 0, 0, 0);
                }
            __builtin_amdgcn_s_setprio(0);

            float sv[4][4];
            const bool maskt = (kbase + 63 > q0);
            #pragma unroll
            for (int nf = 0; nf < 4; ++nf)
                #pragma unroll
                for (int r = 0; r < 4; ++r) {
                    float s = sacc[nf][r];
                    if (maskt) {
                        int qr = q0 + wave * 16 + lg * 4 + r;
                        int kc = kbase + nf * 16 + lr;
                        if (qr < kc) s = -3.0e38f;
                    }
                    sv[nf][r] = s;
                }
            float corr[4];
            #pragma unroll
            for (int r = 0; r < 4; ++r) {
                float v = fmaxf(fmaxf(sv[0][r], sv[1][r]), fmaxf(sv[2][r], sv[3][r]));
                #pragma unroll
                for (int off = 1; off < 16; off <<= 1) v = fmaxf(v, __shfl_xor(v, off));
                float mnew = fmaxf(m_i[r], v);
                corr[r] = __builtin_amdgcn_exp2f((m_i[r] - mnew) * C);
                m_i[r] = mnew;
            }
            float rsum[4] = {0.f, 0.f, 0.f, 0.f};
            #pragma unroll
            for (int nf = 0; nf < 4; ++nf)
                #pragma unroll
                for (int r = 0; r < 4; ++r) {
                    float p = __builtin_amdgcn_exp2f((sv[nf][r] - m_i[r]) * C);
                    rsum[r] += p;
                    int prow = wave * 16 + lg * 4 + r;
                    *(bf16*)(PsB + ((prow * 128 + (nf * 16 + lr) * 2) ^ ((prow & 7) << 4))) = (bf16)p;
                }
            #pragma unroll
            for (int r = 0; r < 4; ++r) {
                float v = rsum[r];
                #pragma unroll
                for (int off = 1; off < 16; off <<= 1) v += __shfl_xor(v, off);
                l_i[r] = l_i[r] * corr[r] + v;
            }
            #pragma unroll
            for (int df = 0; df < 8; ++df)
                #pragma unroll
                for (int r = 0; r < 4; ++r) o[df][r] *= corr[r];

            // O += P @ V
            __builtin_amdgcn_s_setprio(1);
            #pragma unroll
            for (int ks = 0; ks < 2; ++ks) {
                int prow = wave * 16 + lr;
                bf16x8 pf = *(const bf16x8*)(PsB + ((prow * 128 + ks * 64 + lg * 16) ^ ((prow & 7) << 4)));
                #pragma unroll
                for (int df = 0; df < 8; ++df) {
                    int vr2 = df * 16 + lr;
                    bf16x8 vf = *(const bf16x8*)(VB + ((vr2 * 128 + ks * 64 + lg * 16) ^ ((vr2 & 7) << 4)));
                    o[df] = __builtin_amdgcn_mfma_f32_16x16x32_bf16(pf, vf, o[df], 0, 0, 0);
                }
            }
            __builtin_amdgcn_s_setprio(0);
            __syncthreads();   // drains prefetch (vmcnt) + all LDS reads of buf[cur]
            cur ^= 1;
        }

        #pragma unroll
        for (int r = 0; r < 4; ++r) {
            float inv = 1.0f / l_i[r];
            #pragma unroll
            for (int df = 0; df < 8; ++df) {
                int rrow = q0 + wave * 16 + lg * 4 + r;
                int col = h * HDIM + df * 16 + lr;
                ctx[(size_t)(b * SS + rrow) * DOUT + col] = (bf16)(o[df][r] * inv);
            }
        }
    }
}

extern "C" void kernel_launch(void* const* d_in, const int* in_sizes, int n_in,
                              void* d_out, int out_size, void* d_ws, size_t ws_size,
                              hipStream_t stream) {
    const float* x    = (const float*)d_in[0];
    const float* Wq   = (const float*)d_in[1];
    const float* Wdkv = (const float*)d_in[2];
    const float* Wuk  = (const float*)d_in[3];
    const float* Wuv  = (const float*)d_in[4];
    const float* Wout = (const float*)d_in[5];
    const float* bout = (const float*)d_in[6];

    char* ws = (char*)d_ws;
    size_t off = 0;
    auto alloc = [&](size_t bytes) { char* p = ws + off; off = (off + bytes + 255) & ~255ULL; return p; };
    bf16* xb    = (bf16*)alloc((size_t)MTOT * DIN * 2);
    bf16* WqT   = (bf16*)alloc((size_t)DOUT * DIN * 2);     // adjacent:
    bf16* WdkvT = (bf16*)alloc((size_t)LATENT * DIN * 2);   //   WqT||WdkvT = [2304][2048]
    bf16* WukT  = (bf16*)alloc((size_t)DOUT * LATENT * 2);  // adjacent:
    bf16* WuvT  = (bf16*)alloc((size_t)DOUT * LATENT * 2);  //   WukT||WuvT = [4096][256]
    bf16* WoutT = (bf16*)alloc((size_t)DOUT * DOUT * 2);
    bf16* qlat  = (bf16*)alloc((size_t)MTOT * QLD * 2);     // [4096][2304]: q | latent
    bf16* kvb   = (bf16*)alloc((size_t)MTOT * KLD * 2);     // [4096][4096]: k | v
    bf16* vT    = (bf16*)alloc((size_t)BB * NHEADS * HDIM * SS * 2);
    bf16* ctx   = (bf16*)alloc((size_t)MTOT * DOUT * 2);

    cast_f32_bf16<<<(MTOT * DIN) / 8 / 256, 256, 0, stream>>>(x, xb, MTOT * DIN);
    transpose_cast<<<dim3(DOUT / 32, DIN / 32), 256, 0, stream>>>(Wq, WqT, DIN, DOUT);
    transpose_cast<<<dim3(LATENT / 32, DIN / 32), 256, 0, stream>>>(Wdkv, WdkvT, DIN, LATENT);
    transpose_cast<<<dim3(DOUT / 32, LATENT / 32), 256, 0, stream>>>(Wuk, WukT, LATENT, DOUT);
    transpose_cast<<<dim3(DOUT / 32, LATENT / 32), 256, 0, stream>>>(Wuv, WuvT, LATENT, DOUT);
    transpose_cast<<<dim3(DOUT / 32, DOUT / 32), 256, 0, stream>>>(Wout, WoutT, DOUT, DOUT);

    // fused [q | latent] = xb @ [WqT||WdkvT]^T
    gemm_bt<false, false><<<dim3(QLD / 128, MTOT / 128), 256, 0, stream>>>(
        xb, WqT, qlat, nullptr, DIN, DIN, QLD, QLD);
    // fused [k | v] = latent @ [WukT||WuvT]^T
    gemm_bt<false, false><<<dim3(KLD / 128, MTOT / 128), 256, 0, stream>>>(
        qlat + DOUT, WukT, kvb, nullptr, LATENT, QLD, KLD, KLD);

    transpose_v<<<dim3(SS / 32, HDIM / 32, BB * NHEADS), 256, 0, stream>>>(kvb + DOUT, vT);

    attn_kernel<<<dim3(16, BB * NHEADS), 256, 0, stream>>>(qlat, kvb, vT, ctx);

    gemm_bt<true, true><<<dim3(DOUT / 128, MTOT / 128), 256, 0, stream>>>(
        ctx, WoutT, d_out, bout, DOUT, DOUT, DOUT, DOUT);
}